// Round 18
// baseline (208.859 us; speedup 1.0000x reference)
//
#include <hip/hip_runtime.h>
#include <hip/hip_bf16.h>
#include <cstdint>

// ---------------------------------------------------------------------------
// HGAT: 2-layer hetero GAT (user<->movie), H=4 heads, C=32, HC=128.
// Layer-1 GEMM on bf16 MFMA 16x16x32 (folded attention V appended -> hs+att
// in one pass). CSR build: zero-global-atomic LDS counting sort (r15).
// Fused aggs (r16/17): agg1+GEMM2 (writes layer-2 hs/atts/attd via LDS tile
// + MFMA epilogue vs Wb2), agg2+PROJ (writes OU/OM vs Wb_o).
// DUAL-NODE INTERLEAVE (r18): aggs are latency-bound (1.5TB/s at 24% HBM,
// VALU 35%); each 16-lane group now walks TWO nodes' edge lists with
// interleaved 4-deep loops (block covers 32 nodes) -> 8 loads in flight
// instead of 4, effective even at user-side Poisson(5) degrees where
// plain depth-8 was dead code (r6). Per-node edge order unchanged ->
// bit-identical fp32 results.
// REVERTED (net-negative): degree-sort perm (r9/10), src-windowed CSR (r11),
// hist-GEMM fusion (r13/14: returning-atomic floor can't be hidden).
// Softmax max-subtraction skipped (logits bounded; shift-invariant; validated).
// ---------------------------------------------------------------------------

#define HC 128
#define HH 4
#define WPART 256       // key windows (key>>9, covers keys < 131072)
#define EPB 2048        // edges per partition block

typedef __attribute__((ext_vector_type(8))) short bf16x8;
typedef __attribute__((ext_vector_type(4))) float f32x4;

__device__ __forceinline__ short f2bf(float f) {
    return __builtin_bit_cast(short, __float2bfloat16(f));
}
__device__ __forceinline__ float bf2f(ushort u) {
    return __builtin_bit_cast(float, ((unsigned)u) << 16);
}

// ---------------- fold attention: v[k, coff+h] = sum_c W[k,h*32+c]*a[h,c] ---
struct VT { const float* W[8]; const float* a[8]; float* v[8]; };
__global__ void make_v_all_k(VT t) {
    int gid = blockIdx.x * 256 + threadIdx.x;
    int task, base;
    if (gid < 1024) { task = gid >> 8; base = gid & 255; }
    else if (gid < 3072) { int g = gid - 1024; task = 4 + (g >> 9); base = g & 511; }
    else return;
    int k = base >> 2, h = base & 3;
    int coff = (task & 1) * 4;
    const float* wr = t.W[task] + (size_t)k * HC + h * 32;
    const float* ar = t.a[task] + h * 32;
    float s = 0.f;
    #pragma unroll
    for (int c = 0; c < 32; ++c) s = fmaf(wr[c], ar[c], s);
    t.v[task][k * 8 + coff + h] = s;
}

// ---------------- pack Wb[n][k] = bf16(W[k][n]); rows Nw..Nw+7 = V ----------
struct PT { const float* W[5]; const float* V[5]; ushort* Wb[5];
            int K[5]; int Nw[5]; int start[6]; };
__global__ void pack_all_k(PT t) {
    int gid = blockIdx.x * 256 + threadIdx.x;
    if (gid >= t.start[5]) return;
    int task = 0;
    while (gid >= t.start[task + 1]) ++task;
    int loc = gid - t.start[task];
    int K = t.K[task], Nw = t.Nw[task];
    int n = loc / K, k = loc % K;
    float v = 0.f;
    if (n < Nw) v = t.W[task][(size_t)k * Nw + n];
    else if (t.V[task] != nullptr && n < Nw + 8) v = t.V[task][k * 8 + (n - Nw)];
    t.Wb[task][loc] = (ushort)f2bf(v);
}

// ---------------- dual-segment bf16 MFMA GEMM (layer 1) ---------------------
// MODE 0: hs out (bf16 [M,128]) + atts bf16 [M,4] + attd fp32 [M,4].
template <int NT, int MODE, bool ABF>
__global__ __launch_bounds__(256) void gemm_dual_k(
    const void* A0, const int* idx0, const ushort* Wb0, ushort* hsb0,
    ushort* atts0, float* attd0, float* C0, const float* bias0, int M0, int nb0,
    const void* A1, const int* idx1, const ushort* Wb1, ushort* hsb1,
    ushort* atts1, float* attd1, float* C1, const float* bias1, int M1,
    int K, int ldc) {
    const void* A; const int* aidx; const ushort* Wb; ushort* hsb;
    ushort* atts; float* attd; float* C; const float* bias; int M, bid;
    if ((int)blockIdx.x < nb0) {
        A = A0; aidx = idx0; Wb = Wb0; hsb = hsb0; atts = atts0; attd = attd0;
        C = C0; bias = bias0; M = M0; bid = blockIdx.x;
    } else {
        A = A1; aidx = idx1; Wb = Wb1; hsb = hsb1; atts = atts1; attd = attd1;
        C = C1; bias = bias1; M = M1; bid = blockIdx.x - nb0;
    }
    int lane = threadIdx.x & 63;
    int wave = threadIdx.x >> 6;
    int m_base = bid * 128 + wave * 32;
    int lm = lane & 15;      // A row-in-tile / C col-in-tile
    int kg = lane >> 4;      // k-group (8 consecutive k)

    int r0 = m_base + lm, r1 = r0 + 16;
    int cr0 = r0 < M ? r0 : M - 1;
    int cr1 = r1 < M ? r1 : M - 1;
    int row0 = aidx ? aidx[cr0] : cr0;
    int row1 = aidx ? aidx[cr1] : cr1;
    const ushort* bp = Wb + (size_t)lm * K + kg * 8;

    f32x4 acc[2][NT] = {};
    for (int k0 = 0; k0 < K; k0 += 32) {
        bf16x8 a[2];
        if (ABF) {
            const ushort* a0p = (const ushort*)A + (size_t)row0 * K + kg * 8;
            const ushort* a1p = (const ushort*)A + (size_t)row1 * K + kg * 8;
            a[0] = *reinterpret_cast<const bf16x8*>(a0p + k0);
            a[1] = *reinterpret_cast<const bf16x8*>(a1p + k0);
        } else {
            const float* a0p = (const float*)A + (size_t)row0 * K + kg * 8;
            const float* a1p = (const float*)A + (size_t)row1 * K + kg * 8;
            float af[2][8];
            *reinterpret_cast<float4*>(&af[0][0]) = *reinterpret_cast<const float4*>(a0p + k0);
            *reinterpret_cast<float4*>(&af[0][4]) = *reinterpret_cast<const float4*>(a0p + k0 + 4);
            *reinterpret_cast<float4*>(&af[1][0]) = *reinterpret_cast<const float4*>(a1p + k0);
            *reinterpret_cast<float4*>(&af[1][4]) = *reinterpret_cast<const float4*>(a1p + k0 + 4);
            #pragma unroll
            for (int mi = 0; mi < 2; ++mi)
                #pragma unroll
                for (int j = 0; j < 8; ++j) a[mi][j] = f2bf(af[mi][j]);
        }
        #pragma unroll
        for (int nt = 0; nt < NT; ++nt) {
            bf16x8 b = *reinterpret_cast<const bf16x8*>(bp + (size_t)nt * 16 * K + k0);
            acc[0][nt] = __builtin_amdgcn_mfma_f32_16x16x32_bf16(a[0], b, acc[0][nt], 0, 0, 0);
            acc[1][nt] = __builtin_amdgcn_mfma_f32_16x16x32_bf16(a[1], b, acc[1][nt], 0, 0, 0);
        }
    }
    #pragma unroll
    for (int mi = 0; mi < 2; ++mi) {
        int rowb = m_base + mi * 16 + kg * 4;
        if (MODE == 0) {
            #pragma unroll
            for (int nt = 0; nt < NT - 1; ++nt) {
                int col = nt * 16 + lm;
                #pragma unroll
                for (int r = 0; r < 4; ++r) {
                    int row = rowb + r;
                    if (row < M) hsb[(size_t)row * HC + col] = (ushort)f2bf(acc[mi][nt][r]);
                }
            }
            #pragma unroll
            for (int r = 0; r < 4; ++r) {
                int row = rowb + r;
                if (row < M) {
                    float v = acc[mi][NT - 1][r];
                    if (lm < 4) atts[(size_t)row * 4 + lm] = (ushort)f2bf(v);
                    else if (lm < 8) attd[(size_t)row * 4 + (lm - 4)] = v;
                }
            }
        } else {
            #pragma unroll
            for (int nt = 0; nt < NT; ++nt) {
                int col = nt * 16 + lm;
                float bv = bias[col];
                #pragma unroll
                for (int r = 0; r < 4; ++r) {
                    int row = rowb + r;
                    if (row < M) C[(size_t)row * ldc + col] = acc[mi][nt][r] + bv;
                }
            }
        }
    }
}

// ---------------- P1a: per-block window histogram (LDS, no global atomics) --
__global__ __launch_bounds__(256) void part_count_k(
    const int* __restrict__ d0, int E0,
    const int* __restrict__ d1, int E1, int Nm,
    int* __restrict__ cntmat, int NB1) {
    __shared__ int lh[WPART];
    int t = threadIdx.x;
    lh[t] = 0;
    __syncthreads();
    int base = blockIdx.x * EPB + t;
    #pragma unroll
    for (int j = 0; j < EPB / 256; ++j) {
        int e = base + j * 256;
        int key = -1;
        if (e < E0) key = d0[e];
        else if (e - E0 < E1) key = Nm + d1[e - E0];
        if (key >= 0) atomicAdd(&lh[key >> 9], 1);
    }
    __syncthreads();
    cntmat[(size_t)t * NB1 + blockIdx.x] = lh[t];
}

// ---------------- P1b: scatter (src,key) into window partitions -------------
__global__ __launch_bounds__(256) void part_scatter_k(
    const int* __restrict__ s0, const int* __restrict__ d0, int E0,
    const int* __restrict__ s1, const int* __restrict__ d1, int E1, int Nm,
    const int* __restrict__ scanned, int NB1, int2* __restrict__ buf) {
    __shared__ int lb[WPART];
    __shared__ int lc[WPART];
    int t = threadIdx.x;
    lb[t] = scanned[(size_t)t * NB1 + blockIdx.x];
    lc[t] = 0;
    __syncthreads();
    int base = blockIdx.x * EPB + t;
    #pragma unroll
    for (int j = 0; j < EPB / 256; ++j) {
        int e = base + j * 256;
        int key = -1, src = 0;
        if (e < E0) { key = d0[e]; src = s0[e]; }
        else if (e - E0 < E1) { key = Nm + d1[e - E0]; src = s1[e - E0]; }
        if (key >= 0) {
            int w = key >> 9;
            int r = atomicAdd(&lc[w], 1);
            buf[lb[w] + r] = make_int2(src, key);
        }
    }
}

// ---------------- P2: per-window counting sort -> rs + csr ------------------
__global__ __launch_bounds__(512) void csort_k(
    const int2* __restrict__ buf, const int* __restrict__ scanned, int NB1,
    int E, int NK, int* __restrict__ rs, int* __restrict__ csr) {
    __shared__ int c1[512];
    __shared__ int ls[512];
    int b = blockIdx.x;
    int t = threadIdx.x;
    int lo = scanned[(size_t)b * NB1];
    int hi = (b + 1 < WPART) ? scanned[(size_t)(b + 1) * NB1] : E;
    int keylo = b << 9;
    c1[t] = 0;
    __syncthreads();
    for (int i = lo + t; i < hi; i += 512)
        atomicAdd(&c1[buf[i].y - keylo], 1);
    __syncthreads();
    int v = c1[t];
    ls[t] = v;
    __syncthreads();
    for (int off = 1; off < 512; off <<= 1) {
        int x = (t >= off) ? ls[t - off] : 0;
        __syncthreads();
        ls[t] += x;
        __syncthreads();
    }
    ls[t] -= v;            // exclusive
    int gk = keylo + t;
    if (gk <= NK) rs[gk] = lo + ls[t];
    c1[t] = 0;             // reuse as slot counters
    __syncthreads();
    for (int i = lo + t; i < hi; i += 512) {
        int2 p = buf[i];
        int k = p.y - keylo;
        int r = atomicAdd(&c1[k], 1);
        csr[lo + ls[k] + r] = p.x;
    }
}

// ---------------- scan helpers (exclusive, 3-kernel) -------------------------
__global__ void scan_block_k(const int* __restrict__ deg, int n,
                             int* __restrict__ out, int* __restrict__ partial) {
    __shared__ int s[256];
    int i = blockIdx.x * 256 + threadIdx.x;
    int v = (i < n) ? deg[i] : 0;
    s[threadIdx.x] = v;
    __syncthreads();
    for (int off = 1; off < 256; off <<= 1) {
        int x = (threadIdx.x >= off) ? s[threadIdx.x - off] : 0;
        __syncthreads();
        s[threadIdx.x] += x;
        __syncthreads();
    }
    if (i < n) out[i] = s[threadIdx.x] - v;
    if (threadIdx.x == 255) partial[blockIdx.x] = s[255];
}

__global__ void scan_partial_k(int* __restrict__ partial, int nb) {
    __shared__ int s[512];
    int t = threadIdx.x;
    int v = (t < nb) ? partial[t] : 0;
    s[t] = v;
    __syncthreads();
    for (int off = 1; off < 512; off <<= 1) {
        int x = (t >= off) ? s[t - off] : 0;
        __syncthreads();
        s[t] += x;
        __syncthreads();
    }
    if (t < nb) partial[t] = s[t] - v;
}

__global__ void add_off_k(int* __restrict__ out, const int* __restrict__ partial, int n) {
    int i = blockIdx.x * 256 + threadIdx.x;
    if (i < n) out[i] += partial[blockIdx.x];
}

// ---------------- fused aggregation: 16 lanes/node, TWO nodes/lane-group ----
// Block covers 32 nodes (slots 2*gl, 2*gl+1). Interleaved 4-deep gather loops
// give 8 loads in flight. Epilogues (PROJ/GEMM2) use LDS [32][136] + two
// 16-row MFMA halves. Blocks type-pure: [0, blocksM)=movie, rest=user.
template <bool WF32, bool PROJ, bool GEMM2>
__global__ __launch_bounds__(256) void agg32_dual_k(
    const int* __restrict__ rs0, const int* __restrict__ csr0,
    const ushort* __restrict__ hsb0, const ushort* __restrict__ atts0,
    const float* __restrict__ attd0, const float* __restrict__ bias0,
    float* __restrict__ out0, int n0,
    const int* __restrict__ rs1, const int* __restrict__ csr1,
    const ushort* __restrict__ hsb1, const ushort* __restrict__ atts1,
    const float* __restrict__ attd1, const float* __restrict__ bias1,
    float* __restrict__ out1, int n1,
    const ushort* __restrict__ Wbo, const float* __restrict__ bo,
    float* __restrict__ pj0, float* __restrict__ pj1,
    const ushort* __restrict__ W2_0, ushort* __restrict__ hs2_0,
    ushort* __restrict__ atts2_0, float* __restrict__ attd2_0,
    const ushort* __restrict__ W2_1, ushort* __restrict__ hs2_1,
    ushort* __restrict__ atts2_1, float* __restrict__ attd2_1) {
    int blocksM = (n0 + 31) >> 5;
    bool ty1 = (int)blockIdx.x >= blocksM;
    int base = ty1 ? ((int)blockIdx.x - blocksM) * 32 : (int)blockIdx.x * 32;
    int gl = threadIdx.x >> 4;       // lane-group 0..15
    int c  = threadIdx.x & 15;       // channels 8c..8c+7
    int h  = c >> 2;                 // head
    const int* rs = ty1 ? rs1 : rs0;
    const int* csr = ty1 ? csr1 : csr0;
    const ushort* hsb = ty1 ? hsb1 : hsb0;
    const ushort* atts = ty1 ? atts1 : atts0;
    const float* attd = ty1 ? attd1 : attd0;
    const float* bias = ty1 ? bias1 : bias0;
    int n = ty1 ? n1 : n0;
    int nA = base + 2 * gl, nB = nA + 1;
    bool actA = nA < n, actB = nB < n;
    int nAc = actA ? nA : 0, nBc = actB ? nB : 0;

    float adA = attd[nAc * 4 + h];
    float adB = attd[nBc * 4 + h];
    int iA = 0, eA = 0, iB = 0, eB = 0;
    if (actA) { iA = rs[nAc]; eA = rs[nAc + 1]; }
    if (actB) { iB = rs[nBc]; eB = rs[nBc + 1]; }
    float accA[8] = {}, accB[8] = {};
    float wsA = 0.f, wsB = 0.f;

    // fused main loop: both nodes 4-deep -> 8 gathers in flight
    while (iA + 4 <= eA && iB + 4 <= eB) {
        int sxA[4], sxB[4];
        #pragma unroll
        for (int j = 0; j < 4; ++j) { sxA[j] = csr[iA + j]; sxB[j] = csr[iB + j]; }
        bf16x8 hvA[4], hvB[4]; float elA[4], elB[4];
        #pragma unroll
        for (int j = 0; j < 4; ++j) {
            hvA[j] = *reinterpret_cast<const bf16x8*>(hsb + (size_t)sxA[j] * HC + 8 * c);
            elA[j] = bf2f(atts[(size_t)sxA[j] * 4 + h]);
            hvB[j] = *reinterpret_cast<const bf16x8*>(hsb + (size_t)sxB[j] * HC + 8 * c);
            elB[j] = bf2f(atts[(size_t)sxB[j] * 4 + h]);
        }
        #pragma unroll
        for (int j = 0; j < 4; ++j) {
            float e = elA[j] + adA;
            e = e > 0.f ? e : 0.2f * e;
            float w = __expf(e);
            wsA += w;
            #pragma unroll
            for (int k = 0; k < 8; ++k)
                accA[k] = fmaf(w, bf2f((ushort)hvA[j][k]), accA[k]);
        }
        #pragma unroll
        for (int j = 0; j < 4; ++j) {
            float e = elB[j] + adB;
            e = e > 0.f ? e : 0.2f * e;
            float w = __expf(e);
            wsB += w;
            #pragma unroll
            for (int k = 0; k < 8; ++k)
                accB[k] = fmaf(w, bf2f((ushort)hvB[j][k]), accB[k]);
        }
        iA += 4; iB += 4;
    }
    // drain A 4-deep
    for (; iA + 4 <= eA; iA += 4) {
        int sx[4];
        #pragma unroll
        for (int j = 0; j < 4; ++j) sx[j] = csr[iA + j];
        bf16x8 hv[4]; float el[4];
        #pragma unroll
        for (int j = 0; j < 4; ++j) {
            hv[j] = *reinterpret_cast<const bf16x8*>(hsb + (size_t)sx[j] * HC + 8 * c);
            el[j] = bf2f(atts[(size_t)sx[j] * 4 + h]);
        }
        #pragma unroll
        for (int j = 0; j < 4; ++j) {
            float e = el[j] + adA;
            e = e > 0.f ? e : 0.2f * e;
            float w = __expf(e);
            wsA += w;
            #pragma unroll
            for (int k = 0; k < 8; ++k)
                accA[k] = fmaf(w, bf2f((ushort)hv[j][k]), accA[k]);
        }
    }
    // drain B 4-deep
    for (; iB + 4 <= eB; iB += 4) {
        int sx[4];
        #pragma unroll
        for (int j = 0; j < 4; ++j) sx[j] = csr[iB + j];
        bf16x8 hv[4]; float el[4];
        #pragma unroll
        for (int j = 0; j < 4; ++j) {
            hv[j] = *reinterpret_cast<const bf16x8*>(hsb + (size_t)sx[j] * HC + 8 * c);
            el[j] = bf2f(atts[(size_t)sx[j] * 4 + h]);
        }
        #pragma unroll
        for (int j = 0; j < 4; ++j) {
            float e = el[j] + adB;
            e = e > 0.f ? e : 0.2f * e;
            float w = __expf(e);
            wsB += w;
            #pragma unroll
            for (int k = 0; k < 8; ++k)
                accB[k] = fmaf(w, bf2f((ushort)hv[j][k]), accB[k]);
        }
    }
    // scalar tails
    for (; iA < eA; ++iA) {
        int src = csr[iA];
        bf16x8 hv = *reinterpret_cast<const bf16x8*>(hsb + (size_t)src * HC + 8 * c);
        float e = bf2f(atts[(size_t)src * 4 + h]) + adA;
        e = e > 0.f ? e : 0.2f * e;
        float w = __expf(e);
        wsA += w;
        #pragma unroll
        for (int k = 0; k < 8; ++k)
            accA[k] = fmaf(w, bf2f((ushort)hv[k]), accA[k]);
    }
    for (; iB < eB; ++iB) {
        int src = csr[iB];
        bf16x8 hv = *reinterpret_cast<const bf16x8*>(hsb + (size_t)src * HC + 8 * c);
        float e = bf2f(atts[(size_t)src * 4 + h]) + adB;
        e = e > 0.f ? e : 0.2f * e;
        float w = __expf(e);
        wsB += w;
        #pragma unroll
        for (int k = 0; k < 8; ++k)
            accB[k] = fmaf(w, bf2f((ushort)hv[k]), accB[k]);
    }

    float invA = 1.f / (wsA + 1e-16f);
    float invB = 1.f / (wsB + 1e-16f);
    float vA[8], vB[8];
    #pragma unroll
    for (int k = 0; k < 8; ++k) {
        float bk = bias[8 * c + k];
        vA[k] = fmaf(accA[k], invA, bk);
        vA[k] = vA[k] > 0.f ? vA[k] : 0.01f * vA[k];
        vB[k] = fmaf(accB[k], invB, bk);
        vB[k] = vB[k] > 0.f ? vB[k] : 0.01f * vB[k];
    }
    if (WF32) {
        float* out = ty1 ? out1 : out0;
        if (actA) {
            reinterpret_cast<float4*>(out + (size_t)nA * HC + 8 * c)[0] =
                make_float4(vA[0], vA[1], vA[2], vA[3]);
            reinterpret_cast<float4*>(out + (size_t)nA * HC + 8 * c)[1] =
                make_float4(vA[4], vA[5], vA[6], vA[7]);
        }
        if (actB) {
            reinterpret_cast<float4*>(out + (size_t)nB * HC + 8 * c)[0] =
                make_float4(vB[0], vB[1], vB[2], vB[3]);
            reinterpret_cast<float4*>(out + (size_t)nB * HC + 8 * c)[1] =
                make_float4(vB[4], vB[5], vB[6], vB[7]);
        }
    }
    if constexpr (PROJ || GEMM2) {
        __shared__ ushort As[32][136];   // +8 pad
        bf16x8 uA, uB;
        #pragma unroll
        for (int k = 0; k < 8; ++k) {
            uA[k] = actA ? f2bf(vA[k]) : (short)0;
            uB[k] = actB ? f2bf(vB[k]) : (short)0;
        }
        *reinterpret_cast<bf16x8*>(&As[2 * gl][8 * c]) = uA;
        *reinterpret_cast<bf16x8*>(&As[2 * gl + 1][8 * c]) = uB;
        __syncthreads();
        int lane = threadIdx.x & 63;
        int wv = threadIdx.x >> 6;       // wave
        int lm = lane & 15;
        int kg = lane >> 4;
        if constexpr (PROJ) {
            int col = wv * 16 + lm;
            const ushort* bp = Wbo + (size_t)col * HC + kg * 8;
            float bv = bo[col];
            float* pj = ty1 ? pj1 : pj0;
            #pragma unroll
            for (int mi = 0; mi < 2; ++mi) {
                f32x4 pacc = {};
                #pragma unroll
                for (int k0 = 0; k0 < HC; k0 += 32) {
                    bf16x8 a = *reinterpret_cast<const bf16x8*>(&As[mi * 16 + lm][k0 + kg * 8]);
                    bf16x8 b = *reinterpret_cast<const bf16x8*>(bp + k0);
                    pacc = __builtin_amdgcn_mfma_f32_16x16x32_bf16(a, b, pacc, 0, 0, 0);
                }
                #pragma unroll
                for (int r = 0; r < 4; ++r) {
                    int nd = base + mi * 16 + kg * 4 + r;
                    if (nd < n) pj[(size_t)nd * 64 + col] = pacc[r] + bv;
                }
            }
        }
        if constexpr (GEMM2) {
            const ushort* W2 = ty1 ? W2_1 : W2_0;
            ushort* hs2 = ty1 ? hs2_1 : hs2_0;
            ushort* atts2 = ty1 ? atts2_1 : atts2_0;
            float* attd2 = ty1 ? attd2_1 : attd2_0;
            #pragma unroll
            for (int ti = 0; ti < 3; ++ti) {
                int t = wv + ti * 4;             // tiles wv, wv+4, wv+8
                if (t > 8) break;                // only wave 0 does tile 8
                int col = t * 16 + lm;
                const ushort* bp = W2 + (size_t)col * HC + kg * 8;
                #pragma unroll
                for (int mi = 0; mi < 2; ++mi) {
                    f32x4 gacc = {};
                    #pragma unroll
                    for (int k0 = 0; k0 < HC; k0 += 32) {
                        bf16x8 a = *reinterpret_cast<const bf16x8*>(&As[mi * 16 + lm][k0 + kg * 8]);
                        bf16x8 b = *reinterpret_cast<const bf16x8*>(bp + k0);
                        gacc = __builtin_amdgcn_mfma_f32_16x16x32_bf16(a, b, gacc, 0, 0, 0);
                    }
                    #pragma unroll
                    for (int r = 0; r < 4; ++r) {
                        int nd = base + mi * 16 + kg * 4 + r;
                        if (nd < n) {
                            if (t < 8) {
                                hs2[(size_t)nd * HC + col] = (ushort)f2bf(gacc[r]);
                            } else {
                                if (lm < 4) atts2[(size_t)nd * 4 + lm] = (ushort)f2bf(gacc[r]);
                                else if (lm < 8) attd2[(size_t)nd * 4 + (lm - 4)] = gacc[r];
                            }
                        }
                    }
                }
            }
        }
    }
}

// ---------------------------------------------------------------------------
extern "C" void kernel_launch(void* const* d_in, const int* in_sizes, int n_in,
                              void* d_out, int out_size, void* d_ws, size_t ws_size,
                              hipStream_t stream) {
    const int Nu = in_sizes[0];
    const int Nm = in_sizes[1];
    const int E1 = in_sizes[2];   // um edges
    const int E2 = in_sizes[4];   // mu edges
    const int D  = in_sizes[6] / Nu;   // 64
    const int O  = in_sizes[27];       // 64
    const int E  = E1 + E2;
    const int NK = Nm + Nu;       // combined key range

    const int*   user_ids  = (const int*)d_in[0];
    const int*   movie_ids = (const int*)d_in[1];
    const int*   um_src    = (const int*)d_in[2];
    const int*   um_dst    = (const int*)d_in[3];
    const int*   mu_src    = (const int*)d_in[4];
    const int*   mu_dst    = (const int*)d_in[5];
    const float* user_emb  = (const float*)d_in[6];
    const float* movie_emb = (const float*)d_in[7];
    const float* l1_um_Wsrc = (const float*)d_in[8];
    const float* l1_um_Wdst = (const float*)d_in[9];
    const float* l1_um_asrc = (const float*)d_in[10];
    const float* l1_um_adst = (const float*)d_in[11];
    const float* l1_um_b    = (const float*)d_in[12];
    const float* l1_mu_Wsrc = (const float*)d_in[13];
    const float* l1_mu_Wdst = (const float*)d_in[14];
    const float* l1_mu_asrc = (const float*)d_in[15];
    const float* l1_mu_adst = (const float*)d_in[16];
    const float* l1_mu_b    = (const float*)d_in[17];
    const float* l2_um_W    = (const float*)d_in[18];
    const float* l2_um_asrc = (const float*)d_in[19];
    const float* l2_um_adst = (const float*)d_in[20];
    const float* l2_um_b    = (const float*)d_in[21];
    const float* l2_mu_W    = (const float*)d_in[22];
    const float* l2_mu_asrc = (const float*)d_in[23];
    const float* l2_mu_adst = (const float*)d_in[24];
    const float* l2_mu_b    = (const float*)d_in[25];
    const float* Wo         = (const float*)d_in[26];
    const float* bo         = (const float*)d_in[27];

    auto cdiv = [](int a, int b) { return (a + b - 1) / b; };
    const int NB1 = cdiv(E, EPB);            // partition blocks
    const int CM  = WPART * NB1;             // count matrix size

    // ---- workspace carve ----
    char* p = (char*)d_ws;
    auto alloc = [&](size_t bytes) { void* r = p; p += (bytes + 255) & ~(size_t)255; return r; };
    ushort* hs_u  = (ushort*)alloc((size_t)Nu * HC * 2);   // layer-1 hs
    ushort* hs_m  = (ushort*)alloc((size_t)Nm * HC * 2);
    ushort* hs_u2 = (ushort*)alloc((size_t)Nu * HC * 2);   // layer-2 hs
    ushort* hs_m2 = (ushort*)alloc((size_t)Nm * HC * 2);
    ushort* atts_u  = (ushort*)alloc((size_t)Nu * 4 * 2);  // L1 src logits
    ushort* atts_m  = (ushort*)alloc((size_t)Nm * 4 * 2);
    ushort* atts_u2 = (ushort*)alloc((size_t)Nu * 4 * 2);  // L2 src logits
    ushort* atts_m2 = (ushort*)alloc((size_t)Nm * 4 * 2);
    float* attd_u  = (float*)alloc((size_t)Nu * 4 * 4);
    float* attd_m  = (float*)alloc((size_t)Nm * 4 * 4);
    float* attd_u2 = (float*)alloc((size_t)Nu * 4 * 4);
    float* attd_m2 = (float*)alloc((size_t)Nm * 4 * 4);
    float* V_u1  = (float*)alloc((size_t)HC * 8 * 4);
    float* V_m1  = (float*)alloc((size_t)HC * 8 * 4);
    float* V_u2  = (float*)alloc((size_t)HC * 8 * 4);
    float* V_m2  = (float*)alloc((size_t)HC * 8 * 4);
    ushort* Wb_u1 = (ushort*)alloc((size_t)144 * D * 2);
    ushort* Wb_m1 = (ushort*)alloc((size_t)144 * D * 2);
    ushort* Wb_u2 = (ushort*)alloc((size_t)144 * HC * 2);
    ushort* Wb_m2 = (ushort*)alloc((size_t)144 * HC * 2);
    ushort* Wb_o  = (ushort*)alloc((size_t)64 * HC * 2);
    int* rs      = (int*)alloc((size_t)(NK + 2) * 4);
    int* cntmat  = (int*)alloc((size_t)(CM + 256) * 4);
    int* scanned = (int*)alloc((size_t)(CM + 256) * 4);
    int2* buf    = (int2*)alloc((size_t)E * 8);
    int* csr     = (int*)alloc((size_t)E * 4);
    int* part    = (int*)alloc(1024 * 4);

    // ---- fold attention + pack weights (x-independent) ----
    {
        VT vt;
        const float* Ws[8] = {l1_um_Wsrc, l1_mu_Wdst, l1_mu_Wsrc, l1_um_Wdst,
                              l2_um_W, l2_mu_W, l2_mu_W, l2_um_W};
        const float* as[8] = {l1_um_asrc, l1_mu_adst, l1_mu_asrc, l1_um_adst,
                              l2_um_asrc, l2_mu_adst, l2_mu_asrc, l2_um_adst};
        float* vs[8] = {V_u1, V_u1, V_m1, V_m1, V_u2, V_u2, V_m2, V_m2};
        for (int i = 0; i < 8; ++i) { vt.W[i] = Ws[i]; vt.a[i] = as[i]; vt.v[i] = vs[i]; }
        make_v_all_k<<<12, 256, 0, stream>>>(vt);

        PT pt;
        const float* pW[5] = {l1_um_Wsrc, l1_mu_Wsrc, l2_um_W, l2_mu_W, Wo};
        const float* pV[5] = {V_u1, V_m1, V_u2, V_m2, nullptr};
        ushort* pB[5] = {Wb_u1, Wb_m1, Wb_u2, Wb_m2, Wb_o};
        int pK[5] = {D, D, HC, HC, HC};
        int pN[5] = {HC, HC, HC, HC, 64};
        int cum = 0;
        for (int i = 0; i < 5; ++i) {
            pt.W[i] = pW[i]; pt.V[i] = pV[i]; pt.Wb[i] = pB[i];
            pt.K[i] = pK[i]; pt.Nw[i] = pN[i];
            pt.start[i] = cum;
            cum += (i < 4 ? 144 : 64) * pK[i];
        }
        pt.start[5] = cum;
        pack_all_k<<<cdiv(cum, 256), 256, 0, stream>>>(pt);
    }

    // ---- CSR build via LDS counting sort (zero global atomics) ----
    part_count_k<<<NB1, 256, 0, stream>>>(um_dst, E1, mu_dst, E2, Nm, cntmat, NB1);
    {
        int nb = cdiv(CM, 256);
        scan_block_k<<<nb, 256, 0, stream>>>(cntmat, CM, scanned, part);
        scan_partial_k<<<1, 512, 0, stream>>>(part, nb);
        add_off_k<<<nb, 256, 0, stream>>>(scanned, part, CM);
    }
    part_scatter_k<<<NB1, 256, 0, stream>>>(um_src, um_dst, E1, mu_src, mu_dst, E2,
                                            Nm, scanned, NB1, buf);
    csort_k<<<WPART, 512, 0, stream>>>(buf, scanned, NB1, E, NK, rs, csr);

    // output slots: [out_user | out_movie | xu | xm]
    float* OU = (float*)d_out;
    float* OM = OU + (size_t)Nu * O;
    float* XU = OM + (size_t)Nm * O;
    float* XM = XU + (size_t)Nu * HC;

    int gbU = cdiv(Nu, 128), gbM = cdiv(Nm, 128);
    int aggBlocks = cdiv(Nm, 32) + cdiv(Nu, 32);

    // ---- layer 1: A = fp32 embeddings (gathered), K = D ----
    gemm_dual_k<9, 0, false><<<gbU + gbM, 256, 0, stream>>>(
        user_emb, user_ids, Wb_u1, hs_u, atts_u, attd_u, nullptr, nullptr, Nu, gbU,
        movie_emb, movie_ids, Wb_m1, hs_m, atts_m, attd_m, nullptr, nullptr, Nm,
        D, 0);
    // layer-1 agg FUSED with layer-2 GEMM: writes hs2/atts2/attd2 directly
    agg32_dual_k<false, false, true><<<aggBlocks, 256, 0, stream>>>(
        rs, csr, hs_u, atts_u, attd_m, l1_um_b, nullptr, Nm,
        rs + Nm, csr, hs_m, atts_m, attd_u, l1_mu_b, nullptr, Nu,
        nullptr, nullptr, nullptr, nullptr,
        Wb_m2, hs_m2, atts_m2, attd_m2,      // type 0 (movie activations)
        Wb_u2, hs_u2, atts_u2, attd_u2);     // type 1 (user activations)

    // layer-2 agg: fp32 xu/xm outputs + FUSED final projection (OU/OM)
    agg32_dual_k<true, true, false><<<aggBlocks, 256, 0, stream>>>(
        rs, csr, hs_u2, atts_u2, attd_m2, l2_um_b, XM, Nm,
        rs + Nm, csr, hs_m2, atts_m2, attd_u2, l2_mu_b, XU, Nu,
        Wb_o, bo, OM, OU,
        nullptr, nullptr, nullptr, nullptr,
        nullptr, nullptr, nullptr, nullptr);
}

// Round 19
// 202.142 us; speedup vs baseline: 1.0332x; 1.0332x over previous
//
#include <hip/hip_runtime.h>
#include <hip/hip_bf16.h>
#include <cstdint>

// ---------------------------------------------------------------------------
// HGAT: 2-layer hetero GAT (user<->movie), H=4 heads, C=32, HC=128.
// Layer-1 GEMM on bf16 MFMA 16x16x32 (folded attention V appended -> hs+att
// in one pass). CSR build: zero-global-atomic LDS counting sort (r15).
// Fused aggs (r16/17): agg1+GEMM2 (writes layer-2 hs/atts/attd via LDS tile
// + MFMA epilogue vs Wb2), agg2+PROJ (writes OU/OM vs Wb_o).
// AGG CEILING (established r11/r12/r18): the per-dst gather runs at a
// ~1.5 TB/s random-access throughput limit of the L2-miss/L3 path that is
// INVARIANT to occupancy (r18: 2x loads-in-flight at half occupancy = same
// 72.6us), byte-shaving (r12) and locality blocking (r11). This revision
// reverts r18's dual-node interleave to the best-measured r17 structure.
// REVERTED (net-negative/null): degree-sort perm (r9/10), src-windowed CSR
// (r11), hist-GEMM fusion (r13/14), dual-node interleave (r18).
// Softmax max-subtraction skipped (logits bounded; shift-invariant; validated).
// ---------------------------------------------------------------------------

#define HC 128
#define HH 4
#define WPART 256       // key windows (key>>9, covers keys < 131072)
#define EPB 2048        // edges per partition block

typedef __attribute__((ext_vector_type(8))) short bf16x8;
typedef __attribute__((ext_vector_type(4))) float f32x4;

__device__ __forceinline__ short f2bf(float f) {
    return __builtin_bit_cast(short, __float2bfloat16(f));
}
__device__ __forceinline__ float bf2f(ushort u) {
    return __builtin_bit_cast(float, ((unsigned)u) << 16);
}

// ---------------- fold attention: v[k, coff+h] = sum_c W[k,h*32+c]*a[h,c] ---
struct VT { const float* W[8]; const float* a[8]; float* v[8]; };
__global__ void make_v_all_k(VT t) {
    int gid = blockIdx.x * 256 + threadIdx.x;
    int task, base;
    if (gid < 1024) { task = gid >> 8; base = gid & 255; }
    else if (gid < 3072) { int g = gid - 1024; task = 4 + (g >> 9); base = g & 511; }
    else return;
    int k = base >> 2, h = base & 3;
    int coff = (task & 1) * 4;
    const float* wr = t.W[task] + (size_t)k * HC + h * 32;
    const float* ar = t.a[task] + h * 32;
    float s = 0.f;
    #pragma unroll
    for (int c = 0; c < 32; ++c) s = fmaf(wr[c], ar[c], s);
    t.v[task][k * 8 + coff + h] = s;
}

// ---------------- pack Wb[n][k] = bf16(W[k][n]); rows Nw..Nw+7 = V ----------
struct PT { const float* W[5]; const float* V[5]; ushort* Wb[5];
            int K[5]; int Nw[5]; int start[6]; };
__global__ void pack_all_k(PT t) {
    int gid = blockIdx.x * 256 + threadIdx.x;
    if (gid >= t.start[5]) return;
    int task = 0;
    while (gid >= t.start[task + 1]) ++task;
    int loc = gid - t.start[task];
    int K = t.K[task], Nw = t.Nw[task];
    int n = loc / K, k = loc % K;
    float v = 0.f;
    if (n < Nw) v = t.W[task][(size_t)k * Nw + n];
    else if (t.V[task] != nullptr && n < Nw + 8) v = t.V[task][k * 8 + (n - Nw)];
    t.Wb[task][loc] = (ushort)f2bf(v);
}

// ---------------- dual-segment bf16 MFMA GEMM (layer 1 only now) ------------
// MODE 0: hs out (bf16 [M,128]) + atts bf16 [M,4] + attd fp32 [M,4].
template <int NT, int MODE, bool ABF>
__global__ __launch_bounds__(256) void gemm_dual_k(
    const void* A0, const int* idx0, const ushort* Wb0, ushort* hsb0,
    ushort* atts0, float* attd0, float* C0, const float* bias0, int M0, int nb0,
    const void* A1, const int* idx1, const ushort* Wb1, ushort* hsb1,
    ushort* atts1, float* attd1, float* C1, const float* bias1, int M1,
    int K, int ldc) {
    const void* A; const int* aidx; const ushort* Wb; ushort* hsb;
    ushort* atts; float* attd; float* C; const float* bias; int M, bid;
    if ((int)blockIdx.x < nb0) {
        A = A0; aidx = idx0; Wb = Wb0; hsb = hsb0; atts = atts0; attd = attd0;
        C = C0; bias = bias0; M = M0; bid = blockIdx.x;
    } else {
        A = A1; aidx = idx1; Wb = Wb1; hsb = hsb1; atts = atts1; attd = attd1;
        C = C1; bias = bias1; M = M1; bid = blockIdx.x - nb0;
    }
    int lane = threadIdx.x & 63;
    int wave = threadIdx.x >> 6;
    int m_base = bid * 128 + wave * 32;
    int lm = lane & 15;      // A row-in-tile / C col-in-tile
    int kg = lane >> 4;      // k-group (8 consecutive k)

    int r0 = m_base + lm, r1 = r0 + 16;
    int cr0 = r0 < M ? r0 : M - 1;
    int cr1 = r1 < M ? r1 : M - 1;
    int row0 = aidx ? aidx[cr0] : cr0;
    int row1 = aidx ? aidx[cr1] : cr1;
    const ushort* bp = Wb + (size_t)lm * K + kg * 8;

    f32x4 acc[2][NT] = {};
    for (int k0 = 0; k0 < K; k0 += 32) {
        bf16x8 a[2];
        if (ABF) {
            const ushort* a0p = (const ushort*)A + (size_t)row0 * K + kg * 8;
            const ushort* a1p = (const ushort*)A + (size_t)row1 * K + kg * 8;
            a[0] = *reinterpret_cast<const bf16x8*>(a0p + k0);
            a[1] = *reinterpret_cast<const bf16x8*>(a1p + k0);
        } else {
            const float* a0p = (const float*)A + (size_t)row0 * K + kg * 8;
            const float* a1p = (const float*)A + (size_t)row1 * K + kg * 8;
            float af[2][8];
            *reinterpret_cast<float4*>(&af[0][0]) = *reinterpret_cast<const float4*>(a0p + k0);
            *reinterpret_cast<float4*>(&af[0][4]) = *reinterpret_cast<const float4*>(a0p + k0 + 4);
            *reinterpret_cast<float4*>(&af[1][0]) = *reinterpret_cast<const float4*>(a1p + k0);
            *reinterpret_cast<float4*>(&af[1][4]) = *reinterpret_cast<const float4*>(a1p + k0 + 4);
            #pragma unroll
            for (int mi = 0; mi < 2; ++mi)
                #pragma unroll
                for (int j = 0; j < 8; ++j) a[mi][j] = f2bf(af[mi][j]);
        }
        #pragma unroll
        for (int nt = 0; nt < NT; ++nt) {
            bf16x8 b = *reinterpret_cast<const bf16x8*>(bp + (size_t)nt * 16 * K + k0);
            acc[0][nt] = __builtin_amdgcn_mfma_f32_16x16x32_bf16(a[0], b, acc[0][nt], 0, 0, 0);
            acc[1][nt] = __builtin_amdgcn_mfma_f32_16x16x32_bf16(a[1], b, acc[1][nt], 0, 0, 0);
        }
    }
    #pragma unroll
    for (int mi = 0; mi < 2; ++mi) {
        int rowb = m_base + mi * 16 + kg * 4;
        if (MODE == 0) {
            #pragma unroll
            for (int nt = 0; nt < NT - 1; ++nt) {
                int col = nt * 16 + lm;
                #pragma unroll
                for (int r = 0; r < 4; ++r) {
                    int row = rowb + r;
                    if (row < M) hsb[(size_t)row * HC + col] = (ushort)f2bf(acc[mi][nt][r]);
                }
            }
            #pragma unroll
            for (int r = 0; r < 4; ++r) {
                int row = rowb + r;
                if (row < M) {
                    float v = acc[mi][NT - 1][r];
                    if (lm < 4) atts[(size_t)row * 4 + lm] = (ushort)f2bf(v);
                    else if (lm < 8) attd[(size_t)row * 4 + (lm - 4)] = v;
                }
            }
        } else {
            #pragma unroll
            for (int nt = 0; nt < NT; ++nt) {
                int col = nt * 16 + lm;
                float bv = bias[col];
                #pragma unroll
                for (int r = 0; r < 4; ++r) {
                    int row = rowb + r;
                    if (row < M) C[(size_t)row * ldc + col] = acc[mi][nt][r] + bv;
                }
            }
        }
    }
}

// ---------------- P1a: per-block window histogram (LDS, no global atomics) --
__global__ __launch_bounds__(256) void part_count_k(
    const int* __restrict__ d0, int E0,
    const int* __restrict__ d1, int E1, int Nm,
    int* __restrict__ cntmat, int NB1) {
    __shared__ int lh[WPART];
    int t = threadIdx.x;
    lh[t] = 0;
    __syncthreads();
    int base = blockIdx.x * EPB + t;
    #pragma unroll
    for (int j = 0; j < EPB / 256; ++j) {
        int e = base + j * 256;
        int key = -1;
        if (e < E0) key = d0[e];
        else if (e - E0 < E1) key = Nm + d1[e - E0];
        if (key >= 0) atomicAdd(&lh[key >> 9], 1);
    }
    __syncthreads();
    cntmat[(size_t)t * NB1 + blockIdx.x] = lh[t];
}

// ---------------- P1b: scatter (src,key) into window partitions -------------
__global__ __launch_bounds__(256) void part_scatter_k(
    const int* __restrict__ s0, const int* __restrict__ d0, int E0,
    const int* __restrict__ s1, const int* __restrict__ d1, int E1, int Nm,
    const int* __restrict__ scanned, int NB1, int2* __restrict__ buf) {
    __shared__ int lb[WPART];
    __shared__ int lc[WPART];
    int t = threadIdx.x;
    lb[t] = scanned[(size_t)t * NB1 + blockIdx.x];
    lc[t] = 0;
    __syncthreads();
    int base = blockIdx.x * EPB + t;
    #pragma unroll
    for (int j = 0; j < EPB / 256; ++j) {
        int e = base + j * 256;
        int key = -1, src = 0;
        if (e < E0) { key = d0[e]; src = s0[e]; }
        else if (e - E0 < E1) { key = Nm + d1[e - E0]; src = s1[e - E0]; }
        if (key >= 0) {
            int w = key >> 9;
            int r = atomicAdd(&lc[w], 1);
            buf[lb[w] + r] = make_int2(src, key);
        }
    }
}

// ---------------- P2: per-window counting sort -> rs + csr ------------------
__global__ __launch_bounds__(512) void csort_k(
    const int2* __restrict__ buf, const int* __restrict__ scanned, int NB1,
    int E, int NK, int* __restrict__ rs, int* __restrict__ csr) {
    __shared__ int c1[512];
    __shared__ int ls[512];
    int b = blockIdx.x;
    int t = threadIdx.x;
    int lo = scanned[(size_t)b * NB1];
    int hi = (b + 1 < WPART) ? scanned[(size_t)(b + 1) * NB1] : E;
    int keylo = b << 9;
    c1[t] = 0;
    __syncthreads();
    for (int i = lo + t; i < hi; i += 512)
        atomicAdd(&c1[buf[i].y - keylo], 1);
    __syncthreads();
    int v = c1[t];
    ls[t] = v;
    __syncthreads();
    for (int off = 1; off < 512; off <<= 1) {
        int x = (t >= off) ? ls[t - off] : 0;
        __syncthreads();
        ls[t] += x;
        __syncthreads();
    }
    ls[t] -= v;            // exclusive
    int gk = keylo + t;
    if (gk <= NK) rs[gk] = lo + ls[t];
    c1[t] = 0;             // reuse as slot counters
    __syncthreads();
    for (int i = lo + t; i < hi; i += 512) {
        int2 p = buf[i];
        int k = p.y - keylo;
        int r = atomicAdd(&c1[k], 1);
        csr[lo + ls[k] + r] = p.x;
    }
}

// ---------------- scan helpers (exclusive, 3-kernel) -------------------------
__global__ void scan_block_k(const int* __restrict__ deg, int n,
                             int* __restrict__ out, int* __restrict__ partial) {
    __shared__ int s[256];
    int i = blockIdx.x * 256 + threadIdx.x;
    int v = (i < n) ? deg[i] : 0;
    s[threadIdx.x] = v;
    __syncthreads();
    for (int off = 1; off < 256; off <<= 1) {
        int x = (threadIdx.x >= off) ? s[threadIdx.x - off] : 0;
        __syncthreads();
        s[threadIdx.x] += x;
        __syncthreads();
    }
    if (i < n) out[i] = s[threadIdx.x] - v;
    if (threadIdx.x == 255) partial[blockIdx.x] = s[255];
}

__global__ void scan_partial_k(int* __restrict__ partial, int nb) {
    __shared__ int s[512];
    int t = threadIdx.x;
    int v = (t < nb) ? partial[t] : 0;
    s[t] = v;
    __syncthreads();
    for (int off = 1; off < 512; off <<= 1) {
        int x = (t >= off) ? s[t - off] : 0;
        __syncthreads();
        s[t] += x;
        __syncthreads();
    }
    if (t < nb) partial[t] = s[t] - v;
}

__global__ void add_off_k(int* __restrict__ out, const int* __restrict__ partial, int n) {
    int i = blockIdx.x * 256 + threadIdx.x;
    if (i < n) out[i] += partial[blockIdx.x];
}

// ---------------- fused per-dst aggregation ---------------------------------
// 16 lanes/node, ushort8 loads; blocks are type-pure: [0, blocksM) = type 0
// (movie dst), rest = type 1 (user dst).
// GEMM2: after gather, block's 16 activation rows -> LDS -> 9-tile MFMA vs
//   W2 (layer-2 weights + folded V) -> writes hs2 + atts2 + attd2 directly.
// PROJ: same pattern vs Wbo (4 tiles) -> writes final outputs pj.
template <bool WF32, bool PROJ, bool GEMM2>
__global__ __launch_bounds__(256) void agg16_dual_k(
    const int* __restrict__ rs0, const int* __restrict__ csr0,
    const ushort* __restrict__ hsb0, const ushort* __restrict__ atts0,
    const float* __restrict__ attd0, const float* __restrict__ bias0,
    float* __restrict__ out0, int n0,
    const int* __restrict__ rs1, const int* __restrict__ csr1,
    const ushort* __restrict__ hsb1, const ushort* __restrict__ atts1,
    const float* __restrict__ attd1, const float* __restrict__ bias1,
    float* __restrict__ out1, int n1,
    const ushort* __restrict__ Wbo, const float* __restrict__ bo,
    float* __restrict__ pj0, float* __restrict__ pj1,
    const ushort* __restrict__ W2_0, ushort* __restrict__ hs2_0,
    ushort* __restrict__ atts2_0, float* __restrict__ attd2_0,
    const ushort* __restrict__ W2_1, ushort* __restrict__ hs2_1,
    ushort* __restrict__ atts2_1, float* __restrict__ attd2_1) {
    int blocksM = (n0 + 15) >> 4;
    bool ty1 = (int)blockIdx.x >= blocksM;
    int base = ty1 ? ((int)blockIdx.x - blocksM) * 16 : (int)blockIdx.x * 16;
    int gl = threadIdx.x >> 4;       // node slot 0..15
    int c  = threadIdx.x & 15;       // channels 8c..8c+7
    int h  = c >> 2;                 // head
    const int* rs = ty1 ? rs1 : rs0;
    const int* csr = ty1 ? csr1 : csr0;
    const ushort* hsb = ty1 ? hsb1 : hsb0;
    const ushort* atts = ty1 ? atts1 : atts0;
    const float* attd = ty1 ? attd1 : attd0;
    const float* bias = ty1 ? bias1 : bias0;
    int n = ty1 ? n1 : n0;
    int node = base + gl;
    bool active = node < n;
    int nodeC = active ? node : 0;

    float ad = attd[nodeC * 4 + h];
    int s0 = 0, s1 = 0;
    if (active) { s0 = rs[nodeC]; s1 = rs[nodeC + 1]; }
    float acc[8] = {};
    float wsum = 0.f;
    int i = s0;
    for (; i + 4 <= s1; i += 4) {            // 4 edge-rows in flight
        int sx[4];
        #pragma unroll
        for (int j = 0; j < 4; ++j) sx[j] = csr[i + j];
        bf16x8 hv[4]; float el[4];
        #pragma unroll
        for (int j = 0; j < 4; ++j) {
            hv[j] = *reinterpret_cast<const bf16x8*>(hsb + (size_t)sx[j] * HC + 8 * c);
            el[j] = bf2f(atts[(size_t)sx[j] * 4 + h]);
        }
        #pragma unroll
        for (int j = 0; j < 4; ++j) {
            float e = el[j] + ad;
            e = e > 0.f ? e : 0.2f * e;
            float w = __expf(e);
            wsum += w;
            #pragma unroll
            for (int k = 0; k < 8; ++k)
                acc[k] = fmaf(w, bf2f((ushort)hv[j][k]), acc[k]);
        }
    }
    for (; i < s1; ++i) {
        int src = csr[i];
        bf16x8 hv = *reinterpret_cast<const bf16x8*>(hsb + (size_t)src * HC + 8 * c);
        float e = bf2f(atts[(size_t)src * 4 + h]) + ad;
        e = e > 0.f ? e : 0.2f * e;
        float w = __expf(e);
        wsum += w;
        #pragma unroll
        for (int k = 0; k < 8; ++k)
            acc[k] = fmaf(w, bf2f((ushort)hv[k]), acc[k]);
    }
    float inv = 1.f / (wsum + 1e-16f);
    float v[8];
    #pragma unroll
    for (int k = 0; k < 8; ++k) {
        v[k] = fmaf(acc[k], inv, bias[8 * c + k]);
        v[k] = v[k] > 0.f ? v[k] : 0.01f * v[k];
    }
    if (WF32 && active) {
        float* out = ty1 ? out1 : out0;
        float4 o0 = make_float4(v[0], v[1], v[2], v[3]);
        float4 o1 = make_float4(v[4], v[5], v[6], v[7]);
        reinterpret_cast<float4*>(out + (size_t)node * HC + 8 * c)[0] = o0;
        reinterpret_cast<float4*>(out + (size_t)node * HC + 8 * c)[1] = o1;
    }
    if constexpr (PROJ || GEMM2) {
        __shared__ ushort As[16][136];   // +8 pad
        bf16x8 u;
        #pragma unroll
        for (int k = 0; k < 8; ++k) u[k] = active ? f2bf(v[k]) : (short)0;
        *reinterpret_cast<bf16x8*>(&As[gl][8 * c]) = u;
        __syncthreads();
        int lane = threadIdx.x & 63;
        int wv = threadIdx.x >> 6;       // wave
        int lm = lane & 15;
        int kg = lane >> 4;
        if constexpr (PROJ) {
            int col = wv * 16 + lm;
            const ushort* bp = Wbo + (size_t)col * HC + kg * 8;
            f32x4 pacc = {};
            #pragma unroll
            for (int k0 = 0; k0 < HC; k0 += 32) {
                bf16x8 a = *reinterpret_cast<const bf16x8*>(&As[lm][k0 + kg * 8]);
                bf16x8 b = *reinterpret_cast<const bf16x8*>(bp + k0);
                pacc = __builtin_amdgcn_mfma_f32_16x16x32_bf16(a, b, pacc, 0, 0, 0);
            }
            float bv = bo[col];
            float* pj = ty1 ? pj1 : pj0;
            #pragma unroll
            for (int r = 0; r < 4; ++r) {
                int nd = base + kg * 4 + r;
                if (nd < n) pj[(size_t)nd * 64 + col] = pacc[r] + bv;
            }
        }
        if constexpr (GEMM2) {
            const ushort* W2 = ty1 ? W2_1 : W2_0;
            ushort* hs2 = ty1 ? hs2_1 : hs2_0;
            ushort* atts2 = ty1 ? atts2_1 : atts2_0;
            float* attd2 = ty1 ? attd2_1 : attd2_0;
            #pragma unroll
            for (int ti = 0; ti < 3; ++ti) {
                int t = wv + ti * 4;             // tiles wv, wv+4, wv+8
                if (t > 8) break;                // only wave 0 does tile 8
                int col = t * 16 + lm;
                const ushort* bp = W2 + (size_t)col * HC + kg * 8;
                f32x4 gacc = {};
                #pragma unroll
                for (int k0 = 0; k0 < HC; k0 += 32) {
                    bf16x8 a = *reinterpret_cast<const bf16x8*>(&As[lm][k0 + kg * 8]);
                    bf16x8 b = *reinterpret_cast<const bf16x8*>(bp + k0);
                    gacc = __builtin_amdgcn_mfma_f32_16x16x32_bf16(a, b, gacc, 0, 0, 0);
                }
                #pragma unroll
                for (int r = 0; r < 4; ++r) {
                    int nd = base + kg * 4 + r;
                    if (nd < n) {
                        if (t < 8) {
                            hs2[(size_t)nd * HC + col] = (ushort)f2bf(gacc[r]);
                        } else {
                            if (lm < 4) atts2[(size_t)nd * 4 + lm] = (ushort)f2bf(gacc[r]);
                            else if (lm < 8) attd2[(size_t)nd * 4 + (lm - 4)] = gacc[r];
                        }
                    }
                }
            }
        }
    }
}

// ---------------------------------------------------------------------------
extern "C" void kernel_launch(void* const* d_in, const int* in_sizes, int n_in,
                              void* d_out, int out_size, void* d_ws, size_t ws_size,
                              hipStream_t stream) {
    const int Nu = in_sizes[0];
    const int Nm = in_sizes[1];
    const int E1 = in_sizes[2];   // um edges
    const int E2 = in_sizes[4];   // mu edges
    const int D  = in_sizes[6] / Nu;   // 64
    const int O  = in_sizes[27];       // 64
    const int E  = E1 + E2;
    const int NK = Nm + Nu;       // combined key range

    const int*   user_ids  = (const int*)d_in[0];
    const int*   movie_ids = (const int*)d_in[1];
    const int*   um_src    = (const int*)d_in[2];
    const int*   um_dst    = (const int*)d_in[3];
    const int*   mu_src    = (const int*)d_in[4];
    const int*   mu_dst    = (const int*)d_in[5];
    const float* user_emb  = (const float*)d_in[6];
    const float* movie_emb = (const float*)d_in[7];
    const float* l1_um_Wsrc = (const float*)d_in[8];
    const float* l1_um_Wdst = (const float*)d_in[9];
    const float* l1_um_asrc = (const float*)d_in[10];
    const float* l1_um_adst = (const float*)d_in[11];
    const float* l1_um_b    = (const float*)d_in[12];
    const float* l1_mu_Wsrc = (const float*)d_in[13];
    const float* l1_mu_Wdst = (const float*)d_in[14];
    const float* l1_mu_asrc = (const float*)d_in[15];
    const float* l1_mu_adst = (const float*)d_in[16];
    const float* l1_mu_b    = (const float*)d_in[17];
    const float* l2_um_W    = (const float*)d_in[18];
    const float* l2_um_asrc = (const float*)d_in[19];
    const float* l2_um_adst = (const float*)d_in[20];
    const float* l2_um_b    = (const float*)d_in[21];
    const float* l2_mu_W    = (const float*)d_in[22];
    const float* l2_mu_asrc = (const float*)d_in[23];
    const float* l2_mu_adst = (const float*)d_in[24];
    const float* l2_mu_b    = (const float*)d_in[25];
    const float* Wo         = (const float*)d_in[26];
    const float* bo         = (const float*)d_in[27];

    auto cdiv = [](int a, int b) { return (a + b - 1) / b; };
    const int NB1 = cdiv(E, EPB);            // partition blocks
    const int CM  = WPART * NB1;             // count matrix size

    // ---- workspace carve ----
    char* p = (char*)d_ws;
    auto alloc = [&](size_t bytes) { void* r = p; p += (bytes + 255) & ~(size_t)255; return r; };
    ushort* hs_u  = (ushort*)alloc((size_t)Nu * HC * 2);   // layer-1 hs
    ushort* hs_m  = (ushort*)alloc((size_t)Nm * HC * 2);
    ushort* hs_u2 = (ushort*)alloc((size_t)Nu * HC * 2);   // layer-2 hs
    ushort* hs_m2 = (ushort*)alloc((size_t)Nm * HC * 2);
    ushort* atts_u  = (ushort*)alloc((size_t)Nu * 4 * 2);  // L1 src logits
    ushort* atts_m  = (ushort*)alloc((size_t)Nm * 4 * 2);
    ushort* atts_u2 = (ushort*)alloc((size_t)Nu * 4 * 2);  // L2 src logits
    ushort* atts_m2 = (ushort*)alloc((size_t)Nm * 4 * 2);
    float* attd_u  = (float*)alloc((size_t)Nu * 4 * 4);
    float* attd_m  = (float*)alloc((size_t)Nm * 4 * 4);
    float* attd_u2 = (float*)alloc((size_t)Nu * 4 * 4);
    float* attd_m2 = (float*)alloc((size_t)Nm * 4 * 4);
    float* V_u1  = (float*)alloc((size_t)HC * 8 * 4);
    float* V_m1  = (float*)alloc((size_t)HC * 8 * 4);
    float* V_u2  = (float*)alloc((size_t)HC * 8 * 4);
    float* V_m2  = (float*)alloc((size_t)HC * 8 * 4);
    ushort* Wb_u1 = (ushort*)alloc((size_t)144 * D * 2);
    ushort* Wb_m1 = (ushort*)alloc((size_t)144 * D * 2);
    ushort* Wb_u2 = (ushort*)alloc((size_t)144 * HC * 2);
    ushort* Wb_m2 = (ushort*)alloc((size_t)144 * HC * 2);
    ushort* Wb_o  = (ushort*)alloc((size_t)64 * HC * 2);
    int* rs      = (int*)alloc((size_t)(NK + 2) * 4);
    int* cntmat  = (int*)alloc((size_t)(CM + 256) * 4);
    int* scanned = (int*)alloc((size_t)(CM + 256) * 4);
    int2* buf    = (int2*)alloc((size_t)E * 8);
    int* csr     = (int*)alloc((size_t)E * 4);
    int* part    = (int*)alloc(1024 * 4);

    // ---- fold attention + pack weights (x-independent) ----
    {
        VT vt;
        const float* Ws[8] = {l1_um_Wsrc, l1_mu_Wdst, l1_mu_Wsrc, l1_um_Wdst,
                              l2_um_W, l2_mu_W, l2_mu_W, l2_um_W};
        const float* as[8] = {l1_um_asrc, l1_mu_adst, l1_mu_asrc, l1_um_adst,
                              l2_um_asrc, l2_mu_adst, l2_mu_asrc, l2_um_adst};
        float* vs[8] = {V_u1, V_u1, V_m1, V_m1, V_u2, V_u2, V_m2, V_m2};
        for (int i = 0; i < 8; ++i) { vt.W[i] = Ws[i]; vt.a[i] = as[i]; vt.v[i] = vs[i]; }
        make_v_all_k<<<12, 256, 0, stream>>>(vt);

        PT pt;
        const float* pW[5] = {l1_um_Wsrc, l1_mu_Wsrc, l2_um_W, l2_mu_W, Wo};
        const float* pV[5] = {V_u1, V_m1, V_u2, V_m2, nullptr};
        ushort* pB[5] = {Wb_u1, Wb_m1, Wb_u2, Wb_m2, Wb_o};
        int pK[5] = {D, D, HC, HC, HC};
        int pN[5] = {HC, HC, HC, HC, 64};
        int cum = 0;
        for (int i = 0; i < 5; ++i) {
            pt.W[i] = pW[i]; pt.V[i] = pV[i]; pt.Wb[i] = pB[i];
            pt.K[i] = pK[i]; pt.Nw[i] = pN[i];
            pt.start[i] = cum;
            cum += (i < 4 ? 144 : 64) * pK[i];
        }
        pt.start[5] = cum;
        pack_all_k<<<cdiv(cum, 256), 256, 0, stream>>>(pt);
    }

    // ---- CSR build via LDS counting sort (zero global atomics) ----
    part_count_k<<<NB1, 256, 0, stream>>>(um_dst, E1, mu_dst, E2, Nm, cntmat, NB1);
    {
        int nb = cdiv(CM, 256);
        scan_block_k<<<nb, 256, 0, stream>>>(cntmat, CM, scanned, part);
        scan_partial_k<<<1, 512, 0, stream>>>(part, nb);
        add_off_k<<<nb, 256, 0, stream>>>(scanned, part, CM);
    }
    part_scatter_k<<<NB1, 256, 0, stream>>>(um_src, um_dst, E1, mu_src, mu_dst, E2,
                                            Nm, scanned, NB1, buf);
    csort_k<<<WPART, 512, 0, stream>>>(buf, scanned, NB1, E, NK, rs, csr);

    // output slots: [out_user | out_movie | xu | xm]
    float* OU = (float*)d_out;
    float* OM = OU + (size_t)Nu * O;
    float* XU = OM + (size_t)Nm * O;
    float* XM = XU + (size_t)Nu * HC;

    int gbU = cdiv(Nu, 128), gbM = cdiv(Nm, 128);
    int aggBlocks = cdiv(Nm, 16) + cdiv(Nu, 16);

    // ---- layer 1: A = fp32 embeddings (gathered), K = D ----
    gemm_dual_k<9, 0, false><<<gbU + gbM, 256, 0, stream>>>(
        user_emb, user_ids, Wb_u1, hs_u, atts_u, attd_u, nullptr, nullptr, Nu, gbU,
        movie_emb, movie_ids, Wb_m1, hs_m, atts_m, attd_m, nullptr, nullptr, Nm,
        D, 0);
    // layer-1 agg FUSED with layer-2 GEMM: writes hs2/atts2/attd2 directly
    agg16_dual_k<false, false, true><<<aggBlocks, 256, 0, stream>>>(
        rs, csr, hs_u, atts_u, attd_m, l1_um_b, nullptr, Nm,
        rs + Nm, csr, hs_m, atts_m, attd_u, l1_mu_b, nullptr, Nu,
        nullptr, nullptr, nullptr, nullptr,
        Wb_m2, hs_m2, atts_m2, attd_m2,      // type 0 (movie activations)
        Wb_u2, hs_u2, atts_u2, attd_u2);     // type 1 (user activations)

    // layer-2 agg: fp32 xu/xm outputs + FUSED final projection (OU/OM)
    agg16_dual_k<true, true, false><<<aggBlocks, 256, 0, stream>>>(
        rs, csr, hs_u2, atts_u2, attd_m2, l2_um_b, XM, Nm,
        rs + Nm, csr, hs_m2, atts_m2, attd_u2, l2_mu_b, XU, Nu,
        Wb_o, bo, OM, OU,
        nullptr, nullptr, nullptr, nullptr,
        nullptr, nullptr, nullptr, nullptr);
}